// Round 2
// baseline (176.982 us; speedup 1.0000x reference)
//
#include <hip/hip_runtime.h>
#include <stdint.h>

namespace {

constexpr int kB       = 8;
constexpr int kT       = 4096;
constexpr int kC4      = 256;          // 1024 f32 channels as float4
constexpr int kL       = 16;           // timesteps per tile (per-thread registers)
constexpr int kSegPerB = kT / kL;      // 256 tiles per batch chain
constexpr int kTiles   = kB * kSegPerB;// 2048 tiles total

constexpr size_t kStateOff   = 256;    // bytes: counter lives at d_ws[0]
constexpr size_t kStateWords = (size_t)kTiles * 1024;  // one u64 per (tile, channel)

// Decoupled-lookback causal prefix-mean.
// state word per (tile, ch): (float_bits << 32) | tag; tag 0=invalid 1=aggregate 2=inclusive.
__global__ __launch_bounds__(256) void lookback_scan(const float4* __restrict__ x,
                                                     float4* __restrict__ out,
                                                     uint32_t* __restrict__ counter,
                                                     uint64_t* __restrict__ st) {
    // Virtual tile id in dispatch order -> predecessors always already running/done.
    __shared__ uint32_t s_tile;
    if (threadIdx.x == 0) s_tile = atomicAdd(counter, 1u);
    __syncthreads();
    const uint32_t tile = s_tile;
    const int b   = (int)(tile >> 8);            // kSegPerB == 256
    const int seg = (int)(tile & (kSegPerB - 1));
    const int c4  = threadIdx.x;

    // Load tile slice into registers (coalesced: lanes = consecutive float4).
    const size_t base = ((size_t)(b * kT + seg * kL)) * kC4 + c4;
    const float4* p = x + base;
    float4 v[kL];
#pragma unroll
    for (int i = 0; i < kL; ++i) v[i] = p[(size_t)i * kC4];
    // In-place inclusive scan over the tile.
#pragma unroll
    for (int i = 1; i < kL; ++i) {
        v[i].x += v[i - 1].x; v[i].y += v[i - 1].y;
        v[i].z += v[i - 1].z; v[i].w += v[i - 1].w;
    }

    const float agg[4] = { v[kL - 1].x, v[kL - 1].y, v[kL - 1].z, v[kL - 1].w };
    uint64_t* myst = st + ((size_t)tile << 10) + (size_t)c4 * 4;
    const uint32_t firstTag = (seg == 0) ? 2u : 1u;   // tile 0 publishes inclusive directly
#pragma unroll
    for (int j = 0; j < 4; ++j) {
        const uint64_t w = ((uint64_t)__float_as_uint(agg[j]) << 32) | firstTag;
        __hip_atomic_store(&myst[j], w, __ATOMIC_RELAXED, __HIP_MEMORY_SCOPE_AGENT);
    }

    float off[4] = {0.f, 0.f, 0.f, 0.f};
    if (seg > 0) {
#pragma unroll 1
        for (int j = 0; j < 4; ++j) {
            int ps = seg - 1;
            float o = 0.f;
            for (;;) {
                const uint64_t* addr =
                    st + (((size_t)((b << 8) | ps)) << 10) + (size_t)c4 * 4 + j;
                const uint64_t w =
                    __hip_atomic_load(addr, __ATOMIC_RELAXED, __HIP_MEMORY_SCOPE_AGENT);
                const uint32_t tag = (uint32_t)w;
                if (tag == 0u) { __builtin_amdgcn_s_sleep(1); continue; }
                o += __uint_as_float((uint32_t)(w >> 32));
                if (tag == 2u || ps == 0) break;
                --ps;
            }
            off[j] = o;
            const uint64_t w = ((uint64_t)__float_as_uint(o + agg[j]) << 32) | 2u;
            __hip_atomic_store(&myst[j], w, __ATOMIC_RELAXED, __HIP_MEMORY_SCOPE_AGENT);
        }
    }

    // Emit (offset + running) / (t+1).
    float4* o = out + base;
    const int t0 = seg * kL;
#pragma unroll
    for (int i = 0; i < kL; ++i) {
        const float inv = 1.0f / (float)(t0 + i + 1);
        float4 r;
        r.x = (v[i].x + off[0]) * inv;
        r.y = (v[i].y + off[1]) * inv;
        r.z = (v[i].z + off[2]) * inv;
        r.w = (v[i].w + off[3]) * inv;
        o[(size_t)i * kC4] = r;
    }
}

}  // namespace

extern "C" void kernel_launch(void* const* d_in, const int* in_sizes, int n_in,
                              void* d_out, int out_size, void* d_ws, size_t ws_size,
                              hipStream_t stream) {
    const float4* x = (const float4*)d_in[0];
    float4* out     = (float4*)d_out;
    uint32_t* ctr   = (uint32_t*)d_ws;
    uint64_t* st    = (uint64_t*)((char*)d_ws + kStateOff);
    // Zero counter + state tags each launch (graph-capturable async memset, ~17 MB).
    hipMemsetAsync(d_ws, 0, kStateOff + kStateWords * sizeof(uint64_t), stream);
    lookback_scan<<<kTiles, 256, 0, stream>>>(x, out, ctr, st);
}

// Round 3
// 70.007 us; speedup vs baseline: 2.5281x; 2.5281x over previous
//
#include <hip/hip_runtime.h>
#include <stdint.h>

namespace {

constexpr int kB      = 8;
constexpr int kT      = 4096;
constexpr int kC4     = 256;   // 1024 f32 channels viewed as float4
constexpr int kNSeg   = 64;
constexpr int kSegLen = 64;    // kT / kNSeg
constexpr int kCols   = kB * kC4;              // 2048 (b,c4) columns
constexpr size_t kPartF4 = (size_t)kB * kNSeg * kC4;  // 131072 float4s = 2 MiB

// K1: partial[b][seg][c4] = sum over the segment's 64 timesteps (float4-wide).
__global__ __launch_bounds__(256) void seg_sum_kernel(const float4* __restrict__ x,
                                                      float4* __restrict__ part) {
    const int tid = blockIdx.x * 256 + threadIdx.x;        // [0, kB*kNSeg*kC4)
    const int c4  = tid & (kC4 - 1);
    const int seg = (tid >> 8) & (kNSeg - 1);              // uniform per block
    const int b   = tid >> 14;

    const float4* p = x + ((size_t)(b * kT + seg * kSegLen)) * kC4 + c4;
    float sx = 0.f, sy = 0.f, sz = 0.f, sw = 0.f;
#pragma unroll 8
    for (int i = 0; i < kSegLen; ++i) {
        const float4 v = p[(size_t)i * kC4];
        sx += v.x; sy += v.y; sz += v.z; sw += v.w;
    }
    part[tid] = make_float4(sx, sy, sz, sw);
}

// K-mid: excl[b][seg][c4] = sum of part[b][s][c4] for s < seg (exclusive prefix
// along seg). One thread per (b,c4) column; lanes = consecutive c4 -> coalesced.
__global__ __launch_bounds__(64) void seg_prefix_kernel(const float4* __restrict__ part,
                                                        float4* __restrict__ excl) {
    const int col = blockIdx.x * 64 + threadIdx.x;         // [0, kCols)
    const int c4  = col & (kC4 - 1);
    const int b   = col >> 8;
    const float4* p = part + (size_t)b * kNSeg * kC4 + c4;
    float4*       e = excl + (size_t)b * kNSeg * kC4 + c4;
    float rx = 0.f, ry = 0.f, rz = 0.f, rw = 0.f;
#pragma unroll 8
    for (int s = 0; s < kNSeg; ++s) {
        const float4 v = p[(size_t)s * kC4];
        e[(size_t)s * kC4] = make_float4(rx, ry, rz, rw);
        rx += v.x; ry += v.y; rz += v.z; rw += v.w;
    }
}

// K2: off = excl (one load), then rescan segment and write (off+running)/(t+1).
__global__ __launch_bounds__(256) void scan_write_kernel(const float4* __restrict__ x,
                                                         const float4* __restrict__ excl,
                                                         float4* __restrict__ out) {
    const int tid = blockIdx.x * 256 + threadIdx.x;
    const int c4  = tid & (kC4 - 1);
    const int seg = (tid >> 8) & (kNSeg - 1);
    const int b   = tid >> 14;

    const float4 o4 = excl[tid];
    float ox = o4.x, oy = o4.y, oz = o4.z, ow = o4.w;

    const size_t base = ((size_t)(b * kT + seg * kSegLen)) * kC4 + c4;
    const float4* p = x + base;
    float4* o       = out + base;
    const int t0    = seg * kSegLen;
#pragma unroll 4
    for (int i = 0; i < kSegLen; ++i) {
        const float4 v = p[(size_t)i * kC4];
        ox += v.x; oy += v.y; oz += v.z; ow += v.w;
        const float inv = __builtin_amdgcn_rcpf((float)(t0 + i + 1));
        o[(size_t)i * kC4] = make_float4(ox * inv, oy * inv, oz * inv, ow * inv);
    }
}

}  // namespace

extern "C" void kernel_launch(void* const* d_in, const int* in_sizes, int n_in,
                              void* d_out, int out_size, void* d_ws, size_t ws_size,
                              hipStream_t stream) {
    const float4* x = (const float4*)d_in[0];
    float4* out     = (float4*)d_out;
    float4* part    = (float4*)d_ws;                       // 2 MiB
    float4* excl    = part + kPartF4;                      // next 2 MiB
    constexpr int total = kB * kNSeg * kC4;                // 131072 threads
    seg_sum_kernel<<<total / 256, 256, 0, stream>>>(x, part);
    seg_prefix_kernel<<<kCols / 64, 64, 0, stream>>>(part, excl);
    scan_write_kernel<<<total / 256, 256, 0, stream>>>(x, excl, out);
}